// Round 16
// baseline (30.555 us; speedup 1.0000x reference)
//
#include <hip/hip_runtime.h>
#include <math.h>

#define QN 8
#define NDIMS 2
#define LATENT 64
#define OUTC 32     // Q + Q + Q*NDIMS
#define FSTR 24     // floats per point: [0:8) s^2 | [8:16) u*cos | [16:24) u*sin
#define IT 4        // i-rows per block tile in pair kernel  (was 8: TLP x2 test)
#define JPT 2       // j's per thread in pair kernel

// ---------------------------------------------------------------------------
// Phase 1: feature MLP — BYTE-IDENTICAL to round 15 (64 threads/point,
// factorized features). Clean A/B: pair-only change this round.
// ---------------------------------------------------------------------------
__global__ __launch_bounds__(256) void feat_kernel(
    const float* __restrict__ x, const float* __restrict__ y, int n,
    const float* __restrict__ W1, const float* __restrict__ b1,
    const float* __restrict__ W2, const float* __restrict__ b2,
    float* __restrict__ featX, float* __restrict__ featY)
{
    const int tid  = threadIdx.x;
    const int lane = tid & 63;
    const int o    = lane & 31;               // output unit
    const int half = lane >> 5;               // k-half
    const int pt   = blockIdx.x * 4 + (tid >> 6);
    const int npts = 2 * n;
    if (pt >= npts) return;

    const float* p = (pt < n) ? (x + 2 * pt) : (y + 2 * (pt - n));
    const float p0 = p[0], p1 = p[1];

    const float kScale = 1.0507009873554804934193349852946f;
    const float kAlpha = 1.6732632423543772848170429916717f;

    const int kbase = half * 32;
    const float4* w1v = (const float4*)(W1 + 2 * kbase);
    const float4* b1v = (const float4*)(b1 + kbase);
    const float4* w2v = (const float4*)(W2 + o * LATENT + kbase);

    float acc0 = (half == 0) ? b2[o] : 0.f;
    float acc1 = 0.f, acc2 = 0.f, acc3 = 0.f;
    #pragma unroll
    for (int g = 0; g < 8; ++g) {
        float4 wa = w1v[2 * g];
        float4 wb = w1v[2 * g + 1];
        float4 bb = b1v[g];
        float z0 = fmaf(wa.x, p0, fmaf(wa.y, p1, bb.x));
        float z1 = fmaf(wa.z, p0, fmaf(wa.w, p1, bb.y));
        float z2 = fmaf(wb.x, p0, fmaf(wb.y, p1, bb.z));
        float z3 = fmaf(wb.z, p0, fmaf(wb.w, p1, bb.w));
        float h0 = kScale * (z0 > 0.f ? z0 : kAlpha * (__expf(z0) - 1.f));
        float h1 = kScale * (z1 > 0.f ? z1 : kAlpha * (__expf(z1) - 1.f));
        float h2 = kScale * (z2 > 0.f ? z2 : kAlpha * (__expf(z2) - 1.f));
        float h3 = kScale * (z3 > 0.f ? z3 : kAlpha * (__expf(z3) - 1.f));
        float4 w2q = w2v[g];
        acc0 = fmaf(w2q.x, h0, acc0);
        acc1 = fmaf(w2q.y, h1, acc1);
        acc2 = fmaf(w2q.z, h2, acc2);
        acc3 = fmaf(w2q.w, h3, acc3);
    }
    float zsum = (acc0 + acc1) + (acc2 + acc3);
    zsum += __shfl_xor(zsum, 32, 64);
    float av = fmaxf(zsum, 0.f) + __logf(1.f + __expf(-fabsf(zsum)));

    const int q = o & 7;
    float w_ = __shfl(av, q, 64);
    float s_ = __shfl(av, 8 + q, 64);
    float f0 = __shfl(av, 16 + 2 * q, 64);
    float f1 = __shfl(av, 17 + 2 * q, 64);

    float val;
    if (o < 8) {
        val = s_ * s_;
    } else {
        const float TWO_PI  = 6.283185307179586f;
        const float ROOT4_2 = 1.18920711500272107f;
        float u   = w_ * sqrtf(s_) * ROOT4_2;
        float phi = fmaf(f0, p0, f1 * p1);
        float rr  = phi - floorf(phi);
        float ang = TWO_PI * rr;
        val = u * ((o < 16) ? __cosf(ang) : __sinf(ang));
    }
    if (lane < FSTR) {
        float* fo = (pt < n) ? (featX + FSTR * pt) : (featY + FSTR * (pt - n));
        fo[o] = val;
    }
}

// ---------------------------------------------------------------------------
// Phase 2: pair_v6 — IDENTICAL math/structure to r15's pair_v5, but IT=4:
// grid 1024 -> 2048 blocks = 8 blocks/CU = 8 waves/SIMD (2x TLP), half the
// per-thread stall chain. Single-variable latency-bound test.
// out[i,j] = sum_q (inv*e) * (vcA*vcB + vsA*vsB),
//            inv = 1/(ssqA+ssqB), e = exp(-d2*inv)
// ---------------------------------------------------------------------------
__global__ __launch_bounds__(256) void pair_kernel(
    const float* __restrict__ x, const float* __restrict__ y, int n,
    const float* __restrict__ fA, const float* __restrict__ fB,
    float* __restrict__ out)
{
    __shared__ __align__(16) float faS[IT * FSTR];     // 384 B
    __shared__ __align__(16) float xaS[IT * 2];        // 32 B

    const int tid = threadIdx.x;
    const int i0  = blockIdx.y * IT;

    if (tid < IT * 6) {                                 // 24 float4s of fA
        ((float4*)faS)[tid] = ((const float4*)(fA + (size_t)i0 * FSTR))[tid];
    } else if (tid < IT * 6 + IT / 2) {                 // 2 float4s of x
        ((float4*)xaS)[tid - IT * 6] = ((const float4*)(x + 2 * i0))[tid - IT * 6];
    }
    __syncthreads();

    const int j0 = blockIdx.x * (256 * JPT) + tid * JPT;   // 2 contiguous j's
    if (j0 >= n) return;     // no barriers after this point

    float ssB[JPT][QN], vcB[JPT][QN], vsB[JPT][QN];
    float yj0[JPT], yj1[JPT];
    #pragma unroll
    for (int jj = 0; jj < JPT; ++jj) {
        const float4* fb4 = (const float4*)(fB + FSTR * (j0 + jj));
        float4 a0 = fb4[0], a1 = fb4[1];       // ssq
        float4 a2 = fb4[2], a3 = fb4[3];       // vc
        float4 a4 = fb4[4], a5 = fb4[5];       // vs
        ssB[jj][0]=a0.x; ssB[jj][1]=a0.y; ssB[jj][2]=a0.z; ssB[jj][3]=a0.w;
        ssB[jj][4]=a1.x; ssB[jj][5]=a1.y; ssB[jj][6]=a1.z; ssB[jj][7]=a1.w;
        vcB[jj][0]=a2.x; vcB[jj][1]=a2.y; vcB[jj][2]=a2.z; vcB[jj][3]=a2.w;
        vcB[jj][4]=a3.x; vcB[jj][5]=a3.y; vcB[jj][6]=a3.z; vcB[jj][7]=a3.w;
        vsB[jj][0]=a4.x; vsB[jj][1]=a4.y; vsB[jj][2]=a4.z; vsB[jj][3]=a4.w;
        vsB[jj][4]=a5.x; vsB[jj][5]=a5.y; vsB[jj][6]=a5.z; vsB[jj][7]=a5.w;
        float2 yv = *(const float2*)(y + 2 * (j0 + jj));
        yj0[jj] = yv.x; yj1[jj] = yv.y;
    }

    const float NLOG2E = -1.4426950408889634f;

    #pragma unroll
    for (int ii = 0; ii < IT; ++ii) {
        int i = i0 + ii;
        if (i >= n) break;

        const float4* fa4 = (const float4*)(faS + ii * FSTR);
        float4 b0 = fa4[0], b1v = fa4[1];
        float4 b2v = fa4[2], b3 = fa4[3];
        float4 b4 = fa4[4], b5 = fa4[5];
        float ssA[QN] = {b0.x,b0.y,b0.z,b0.w, b1v.x,b1v.y,b1v.z,b1v.w};
        float vcA[QN] = {b2v.x,b2v.y,b2v.z,b2v.w, b3.x,b3.y,b3.z,b3.w};
        float vsA[QN] = {b4.x,b4.y,b4.z,b4.w, b5.x,b5.y,b5.z,b5.w};
        float xi0 = xaS[2 * ii], xi1 = xaS[2 * ii + 1];

        float d2ln[JPT];
        #pragma unroll
        for (int jj = 0; jj < JPT; ++jj) {
            float dx = xi0 - yj0[jj];
            float dy = xi1 - yj1[jj];
            d2ln[jj] = fmaf(dx, dx, dy * dy) * NLOG2E;   // -d2*log2(e)
        }

        float2 accv;
        float* accp = &accv.x;
        #pragma unroll
        for (int jj = 0; jj < JPT; ++jj) {
            float acc = 0.f;
            #pragma unroll
            for (int q = 0; q < QN; ++q) {
                float s2  = ssA[q] + ssB[jj][q];
                float inv = __builtin_amdgcn_rcpf(s2);
                float e   = __builtin_amdgcn_exp2f(d2ln[jj] * inv);
                float w   = inv * e;
                float c   = fmaf(vcA[q], vcB[jj][q], vsA[q] * vsB[jj][q]);
                acc = fmaf(w, c, acc);
            }
            accp[jj] = acc;
        }
        *(float2*)(out + (long)i * n + j0) = accv;
    }
}

extern "C" void kernel_launch(void* const* d_in, const int* in_sizes, int n_in,
                              void* d_out, int out_size, void* d_ws, size_t ws_size,
                              hipStream_t stream)
{
    const float* x  = (const float*)d_in[0];
    const float* y  = (const float*)d_in[1];
    const float* W1 = (const float*)d_in[2];
    const float* b1 = (const float*)d_in[3];
    const float* W2 = (const float*)d_in[4];
    const float* b2 = (const float*)d_in[5];
    float* out = (float*)d_out;

    int n = in_sizes[0] / NDIMS;     // 2048

    float* featX = (float*)d_ws;
    float* featY = featX + (size_t)n * FSTR;

    int npts = 2 * n;
    hipLaunchKernelGGL(feat_kernel, dim3((npts + 3) / 4), dim3(256), 0, stream,
                       x, y, n, W1, b1, W2, b2, featX, featY);

    dim3 grid((n + 256 * JPT - 1) / (256 * JPT), (n + IT - 1) / IT);
    hipLaunchKernelGGL(pair_kernel, grid, dim3(256), 0, stream,
                       x, y, n, featX, featY, out);
}

// Round 17
// 27.547 us; speedup vs baseline: 1.1092x; 1.1092x over previous
//
#include <hip/hip_runtime.h>
#include <math.h>

#define QN 8
#define NDIMS 2
#define LATENT 64
#define OUTC 32     // Q + Q + Q*NDIMS
#define FSTR 24     // floats per point: [0:8) s^2 | [8:16) u*cos | [16:24) u*sin
#define IT 16       // i-rows per block tile in pair kernel
#define JPT 1       // j's per thread (JPT=1: B-state 26 regs -> 64-VGPR target)

// ---------------------------------------------------------------------------
// Phase 1: feature MLP — BYTE-IDENTICAL to round 15 (64 threads/point,
// factorized features). Clean A/B: pair-only change this round.
// ---------------------------------------------------------------------------
__global__ __launch_bounds__(256) void feat_kernel(
    const float* __restrict__ x, const float* __restrict__ y, int n,
    const float* __restrict__ W1, const float* __restrict__ b1,
    const float* __restrict__ W2, const float* __restrict__ b2,
    float* __restrict__ featX, float* __restrict__ featY)
{
    const int tid  = threadIdx.x;
    const int lane = tid & 63;
    const int o    = lane & 31;               // output unit
    const int half = lane >> 5;               // k-half
    const int pt   = blockIdx.x * 4 + (tid >> 6);
    const int npts = 2 * n;
    if (pt >= npts) return;

    const float* p = (pt < n) ? (x + 2 * pt) : (y + 2 * (pt - n));
    const float p0 = p[0], p1 = p[1];

    const float kScale = 1.0507009873554804934193349852946f;
    const float kAlpha = 1.6732632423543772848170429916717f;

    const int kbase = half * 32;
    const float4* w1v = (const float4*)(W1 + 2 * kbase);
    const float4* b1v = (const float4*)(b1 + kbase);
    const float4* w2v = (const float4*)(W2 + o * LATENT + kbase);

    float acc0 = (half == 0) ? b2[o] : 0.f;
    float acc1 = 0.f, acc2 = 0.f, acc3 = 0.f;
    #pragma unroll
    for (int g = 0; g < 8; ++g) {
        float4 wa = w1v[2 * g];
        float4 wb = w1v[2 * g + 1];
        float4 bb = b1v[g];
        float z0 = fmaf(wa.x, p0, fmaf(wa.y, p1, bb.x));
        float z1 = fmaf(wa.z, p0, fmaf(wa.w, p1, bb.y));
        float z2 = fmaf(wb.x, p0, fmaf(wb.y, p1, bb.z));
        float z3 = fmaf(wb.z, p0, fmaf(wb.w, p1, bb.w));
        float h0 = kScale * (z0 > 0.f ? z0 : kAlpha * (__expf(z0) - 1.f));
        float h1 = kScale * (z1 > 0.f ? z1 : kAlpha * (__expf(z1) - 1.f));
        float h2 = kScale * (z2 > 0.f ? z2 : kAlpha * (__expf(z2) - 1.f));
        float h3 = kScale * (z3 > 0.f ? z3 : kAlpha * (__expf(z3) - 1.f));
        float4 w2q = w2v[g];
        acc0 = fmaf(w2q.x, h0, acc0);
        acc1 = fmaf(w2q.y, h1, acc1);
        acc2 = fmaf(w2q.z, h2, acc2);
        acc3 = fmaf(w2q.w, h3, acc3);
    }
    float zsum = (acc0 + acc1) + (acc2 + acc3);
    zsum += __shfl_xor(zsum, 32, 64);
    float av = fmaxf(zsum, 0.f) + __logf(1.f + __expf(-fabsf(zsum)));

    const int q = o & 7;
    float w_ = __shfl(av, q, 64);
    float s_ = __shfl(av, 8 + q, 64);
    float f0 = __shfl(av, 16 + 2 * q, 64);
    float f1 = __shfl(av, 17 + 2 * q, 64);

    float val;
    if (o < 8) {
        val = s_ * s_;
    } else {
        const float TWO_PI  = 6.283185307179586f;
        const float ROOT4_2 = 1.18920711500272107f;
        float u   = w_ * sqrtf(s_) * ROOT4_2;
        float phi = fmaf(f0, p0, f1 * p1);
        float rr  = phi - floorf(phi);
        float ang = TWO_PI * rr;
        val = u * ((o < 16) ? __cosf(ang) : __sinf(ang));
    }
    if (lane < FSTR) {
        float* fo = (pt < n) ? (featX + FSTR * pt) : (featY + FSTR * (pt - n));
        fo[o] = val;
    }
}

// ---------------------------------------------------------------------------
// Phase 2: pair_v7 — engineered for the 64-VGPR occupancy step:
//   JPT=1 (B-state = 24 + y = 26 regs), IT=16 (2x per-block amortization),
//   A-side consumed directly from float4 LDS broadcasts (<=3 live float4s),
//   single accumulator, __launch_bounds__(256,8) pins 8 waves/SIMD — the
//   first pair variant to actually run above 4 waves/SIMD.
// out[i,j] = sum_q (inv*e) * (vcA*vcB + vsA*vsB),
//            inv = 1/(ssqA+ssqB), e = exp(-d2*inv)
// ---------------------------------------------------------------------------
__global__ __launch_bounds__(256, 8) void pair_kernel(
    const float* __restrict__ x, const float* __restrict__ y, int n,
    const float* __restrict__ fA, const float* __restrict__ fB,
    float* __restrict__ out)
{
    __shared__ __align__(16) float faS[IT * FSTR];     // 1536 B
    __shared__ __align__(16) float xaS[IT * 2];        // 128 B

    const int tid = threadIdx.x;
    const int i0  = blockIdx.y * IT;

    // ---- cooperative stage of the i-tile (coalesced float4) ----
    if (tid < IT * 6) {                                 // 96 float4s of fA
        ((float4*)faS)[tid] = ((const float4*)(fA + (size_t)i0 * FSTR))[tid];
    } else if (tid < IT * 6 + IT / 2) {                 // 8 float4s of x
        ((float4*)xaS)[tid - IT * 6] = ((const float4*)(x + 2 * i0))[tid - IT * 6];
    }
    __syncthreads();

    const int j = blockIdx.x * 256 + tid;               // JPT=1
    if (j >= n) return;     // no barriers after this point

    // ---- B-side features: 6 float4 -> 24 named scalars (26 regs w/ y) ----
    const float4* fb4 = (const float4*)(fB + FSTR * j);
    float4 a0 = fb4[0], a1 = fb4[1];       // ssq
    float4 a2 = fb4[2], a3 = fb4[3];       // vc
    float4 a4 = fb4[4], a5 = fb4[5];       // vs
    float ssB[QN] = {a0.x,a0.y,a0.z,a0.w, a1.x,a1.y,a1.z,a1.w};
    float vcB[QN] = {a2.x,a2.y,a2.z,a2.w, a3.x,a3.y,a3.z,a3.w};
    float vsB[QN] = {a4.x,a4.y,a4.z,a4.w, a5.x,a5.y,a5.z,a5.w};
    float2 yv = *(const float2*)(y + 2 * j);

    const float NLOG2E = -1.4426950408889634f;

    #pragma unroll 4
    for (int ii = 0; ii < IT; ++ii) {
        int i = i0 + ii;
        if (i >= n) break;

        const float4* fa4 = (const float4*)(faS + ii * FSTR);
        float xi0 = xaS[2 * ii], xi1 = xaS[2 * ii + 1];
        float dx  = xi0 - yv.x;
        float dy  = xi1 - yv.y;
        float d2l = fmaf(dx, dx, dy * dy) * NLOG2E;     // -d2*log2(e)

        float acc = 0.f;
        #pragma unroll
        for (int g = 0; g < 2; ++g) {                   // q-groups of 4
            float4 ssv = fa4[g];                        // broadcast ds_read
            float4 vcv = fa4[2 + g];
            float4 vsv = fa4[4 + g];
            {
                float s2  = ssv.x + ssB[4*g+0];
                float inv = __builtin_amdgcn_rcpf(s2);
                float e   = __builtin_amdgcn_exp2f(d2l * inv);
                acc = fmaf(inv * e, fmaf(vcv.x, vcB[4*g+0], vsv.x * vsB[4*g+0]), acc);
            }
            {
                float s2  = ssv.y + ssB[4*g+1];
                float inv = __builtin_amdgcn_rcpf(s2);
                float e   = __builtin_amdgcn_exp2f(d2l * inv);
                acc = fmaf(inv * e, fmaf(vcv.y, vcB[4*g+1], vsv.y * vsB[4*g+1]), acc);
            }
            {
                float s2  = ssv.z + ssB[4*g+2];
                float inv = __builtin_amdgcn_rcpf(s2);
                float e   = __builtin_amdgcn_exp2f(d2l * inv);
                acc = fmaf(inv * e, fmaf(vcv.z, vcB[4*g+2], vsv.z * vsB[4*g+2]), acc);
            }
            {
                float s2  = ssv.w + ssB[4*g+3];
                float inv = __builtin_amdgcn_rcpf(s2);
                float e   = __builtin_amdgcn_exp2f(d2l * inv);
                acc = fmaf(inv * e, fmaf(vcv.w, vcB[4*g+3], vsv.w * vsB[4*g+3]), acc);
            }
        }
        out[(long)i * n + j] = acc;
    }
}

extern "C" void kernel_launch(void* const* d_in, const int* in_sizes, int n_in,
                              void* d_out, int out_size, void* d_ws, size_t ws_size,
                              hipStream_t stream)
{
    const float* x  = (const float*)d_in[0];
    const float* y  = (const float*)d_in[1];
    const float* W1 = (const float*)d_in[2];
    const float* b1 = (const float*)d_in[3];
    const float* W2 = (const float*)d_in[4];
    const float* b2 = (const float*)d_in[5];
    float* out = (float*)d_out;

    int n = in_sizes[0] / NDIMS;     // 2048

    float* featX = (float*)d_ws;
    float* featY = featX + (size_t)n * FSTR;

    int npts = 2 * n;
    hipLaunchKernelGGL(feat_kernel, dim3((npts + 3) / 4), dim3(256), 0, stream,
                       x, y, n, W1, b1, W2, b2, featX, featY);

    dim3 grid((n + 255) / 256, (n + IT - 1) / IT);
    hipLaunchKernelGGL(pair_kernel, grid, dim3(256), 0, stream,
                       x, y, n, featX, featY, out);
}

// Round 18
// 26.690 us; speedup vs baseline: 1.1448x; 1.0321x over previous
//
#include <hip/hip_runtime.h>
#include <math.h>

#define QN 8
#define NDIMS 2
#define LATENT 64
#define OUTC 32     // Q + Q + Q*NDIMS
#define FSTR 24     // floats per point: [0:8) s^2 | [8:16) u*cos | [16:24) u*sin
#define IT 8        // i-rows per block tile in pair kernel
#define JPT 2       // j's per thread in pair kernel

// ---------------------------------------------------------------------------
// BEST-MEASURED CONFIG (round 15, 26.69 us) — restored verbatim.
// Phase 1: feature MLP — 64 threads/point (thread = (pt, o, k-half)),
// 4 waves/SIMD, no LDS/barrier; factorized features:
//   ssq[q] = s^2 ; vc[q] = u*cos(2pi phi) ; vs[q] = u*sin(2pi phi),
//   u = w*sqrt(s)*2^.25  =>  pair's cosine term becomes vcA*vcB + vsA*vsB.
// ---------------------------------------------------------------------------
__global__ __launch_bounds__(256) void feat_kernel(
    const float* __restrict__ x, const float* __restrict__ y, int n,
    const float* __restrict__ W1, const float* __restrict__ b1,
    const float* __restrict__ W2, const float* __restrict__ b2,
    float* __restrict__ featX, float* __restrict__ featY)
{
    const int tid  = threadIdx.x;
    const int lane = tid & 63;
    const int o    = lane & 31;               // output unit
    const int half = lane >> 5;               // k-half
    const int pt   = blockIdx.x * 4 + (tid >> 6);
    const int npts = 2 * n;
    if (pt >= npts) return;

    const float* p = (pt < n) ? (x + 2 * pt) : (y + 2 * (pt - n));
    const float p0 = p[0], p1 = p[1];

    const float kScale = 1.0507009873554804934193349852946f;
    const float kAlpha = 1.6732632423543772848170429916717f;

    const int kbase = half * 32;
    const float4* w1v = (const float4*)(W1 + 2 * kbase);
    const float4* b1v = (const float4*)(b1 + kbase);
    const float4* w2v = (const float4*)(W2 + o * LATENT + kbase);

    float acc0 = (half == 0) ? b2[o] : 0.f;
    float acc1 = 0.f, acc2 = 0.f, acc3 = 0.f;
    #pragma unroll
    for (int g = 0; g < 8; ++g) {
        float4 wa = w1v[2 * g];
        float4 wb = w1v[2 * g + 1];
        float4 bb = b1v[g];
        float z0 = fmaf(wa.x, p0, fmaf(wa.y, p1, bb.x));
        float z1 = fmaf(wa.z, p0, fmaf(wa.w, p1, bb.y));
        float z2 = fmaf(wb.x, p0, fmaf(wb.y, p1, bb.z));
        float z3 = fmaf(wb.z, p0, fmaf(wb.w, p1, bb.w));
        float h0 = kScale * (z0 > 0.f ? z0 : kAlpha * (__expf(z0) - 1.f));
        float h1 = kScale * (z1 > 0.f ? z1 : kAlpha * (__expf(z1) - 1.f));
        float h2 = kScale * (z2 > 0.f ? z2 : kAlpha * (__expf(z2) - 1.f));
        float h3 = kScale * (z3 > 0.f ? z3 : kAlpha * (__expf(z3) - 1.f));
        float4 w2q = w2v[g];
        acc0 = fmaf(w2q.x, h0, acc0);
        acc1 = fmaf(w2q.y, h1, acc1);
        acc2 = fmaf(w2q.z, h2, acc2);
        acc3 = fmaf(w2q.w, h3, acc3);
    }
    float zsum = (acc0 + acc1) + (acc2 + acc3);
    zsum += __shfl_xor(zsum, 32, 64);         // combine the two k-halves
    float av = fmaxf(zsum, 0.f) + __logf(1.f + __expf(-fabsf(zsum)));

    const int q = o & 7;
    float w_ = __shfl(av, q, 64);
    float s_ = __shfl(av, 8 + q, 64);
    float f0 = __shfl(av, 16 + 2 * q, 64);
    float f1 = __shfl(av, 17 + 2 * q, 64);

    float val;
    if (o < 8) {
        val = s_ * s_;
    } else {
        const float TWO_PI  = 6.283185307179586f;
        const float ROOT4_2 = 1.18920711500272107f;   // 2^(1/4)
        float u   = w_ * sqrtf(s_) * ROOT4_2;
        float phi = fmaf(f0, p0, f1 * p1);
        float rr  = phi - floorf(phi);        // [0,1) revolutions
        float ang = TWO_PI * rr;
        val = u * ((o < 16) ? __cosf(ang) : __sinf(ang));
    }
    if (lane < FSTR) {
        float* fo = (pt < n) ? (featX + FSTR * pt) : (featY + FSTR * (pt - n));
        fo[o] = val;                          // coalesced 96B per point
    }
}

// ---------------------------------------------------------------------------
// Phase 2: pair_v5 (r15) — JPT=2, IT=8, factorized features.
// out[i,j] = sum_q (inv*e) * (vcA*vcB + vsA*vsB),
//            inv = 1/(ssqA+ssqB), e = exp(-d2*inv)
// ---------------------------------------------------------------------------
__global__ __launch_bounds__(256) void pair_kernel(
    const float* __restrict__ x, const float* __restrict__ y, int n,
    const float* __restrict__ fA, const float* __restrict__ fB,
    float* __restrict__ out)
{
    __shared__ __align__(16) float faS[IT * FSTR];     // 768 B
    __shared__ __align__(16) float xaS[IT * 2];        // 64 B

    const int tid = threadIdx.x;
    const int i0  = blockIdx.y * IT;

    if (tid < IT * 6) {                                 // 48 float4s of fA
        ((float4*)faS)[tid] = ((const float4*)(fA + (size_t)i0 * FSTR))[tid];
    } else if (tid < IT * 6 + IT / 2) {                 // 4 float4s of x
        ((float4*)xaS)[tid - IT * 6] = ((const float4*)(x + 2 * i0))[tid - IT * 6];
    }
    __syncthreads();

    const int j0 = blockIdx.x * (256 * JPT) + tid * JPT;   // 2 contiguous j's
    if (j0 >= n) return;     // no barriers after this point

    float ssB[JPT][QN], vcB[JPT][QN], vsB[JPT][QN];
    float yj0[JPT], yj1[JPT];
    #pragma unroll
    for (int jj = 0; jj < JPT; ++jj) {
        const float4* fb4 = (const float4*)(fB + FSTR * (j0 + jj));
        float4 a0 = fb4[0], a1 = fb4[1];       // ssq
        float4 a2 = fb4[2], a3 = fb4[3];       // vc
        float4 a4 = fb4[4], a5 = fb4[5];       // vs
        ssB[jj][0]=a0.x; ssB[jj][1]=a0.y; ssB[jj][2]=a0.z; ssB[jj][3]=a0.w;
        ssB[jj][4]=a1.x; ssB[jj][5]=a1.y; ssB[jj][6]=a1.z; ssB[jj][7]=a1.w;
        vcB[jj][0]=a2.x; vcB[jj][1]=a2.y; vcB[jj][2]=a2.z; vcB[jj][3]=a2.w;
        vcB[jj][4]=a3.x; vcB[jj][5]=a3.y; vcB[jj][6]=a3.z; vcB[jj][7]=a3.w;
        vsB[jj][0]=a4.x; vsB[jj][1]=a4.y; vsB[jj][2]=a4.z; vsB[jj][3]=a4.w;
        vsB[jj][4]=a5.x; vsB[jj][5]=a5.y; vsB[jj][6]=a5.z; vsB[jj][7]=a5.w;
        float2 yv = *(const float2*)(y + 2 * (j0 + jj));
        yj0[jj] = yv.x; yj1[jj] = yv.y;
    }

    const float NLOG2E = -1.4426950408889634f;

    #pragma unroll 2
    for (int ii = 0; ii < IT; ++ii) {
        int i = i0 + ii;
        if (i >= n) break;

        const float4* fa4 = (const float4*)(faS + ii * FSTR);
        float4 b0 = fa4[0], b1v = fa4[1];
        float4 b2v = fa4[2], b3 = fa4[3];
        float4 b4 = fa4[4], b5 = fa4[5];
        float ssA[QN] = {b0.x,b0.y,b0.z,b0.w, b1v.x,b1v.y,b1v.z,b1v.w};
        float vcA[QN] = {b2v.x,b2v.y,b2v.z,b2v.w, b3.x,b3.y,b3.z,b3.w};
        float vsA[QN] = {b4.x,b4.y,b4.z,b4.w, b5.x,b5.y,b5.z,b5.w};
        float xi0 = xaS[2 * ii], xi1 = xaS[2 * ii + 1];

        float d2ln[JPT];
        #pragma unroll
        for (int jj = 0; jj < JPT; ++jj) {
            float dx = xi0 - yj0[jj];
            float dy = xi1 - yj1[jj];
            d2ln[jj] = fmaf(dx, dx, dy * dy) * NLOG2E;   // -d2*log2(e)
        }

        float2 accv;
        float* accp = &accv.x;
        #pragma unroll
        for (int jj = 0; jj < JPT; ++jj) {
            float acc = 0.f;
            #pragma unroll
            for (int q = 0; q < QN; ++q) {
                float s2  = ssA[q] + ssB[jj][q];
                float inv = __builtin_amdgcn_rcpf(s2);
                float e   = __builtin_amdgcn_exp2f(d2ln[jj] * inv);
                float w   = inv * e;
                float c   = fmaf(vcA[q], vcB[jj][q], vsA[q] * vsB[jj][q]);
                acc = fmaf(w, c, acc);
            }
            accp[jj] = acc;
        }
        *(float2*)(out + (long)i * n + j0) = accv;
    }
}

extern "C" void kernel_launch(void* const* d_in, const int* in_sizes, int n_in,
                              void* d_out, int out_size, void* d_ws, size_t ws_size,
                              hipStream_t stream)
{
    const float* x  = (const float*)d_in[0];
    const float* y  = (const float*)d_in[1];
    const float* W1 = (const float*)d_in[2];
    const float* b1 = (const float*)d_in[3];
    const float* W2 = (const float*)d_in[4];
    const float* b2 = (const float*)d_in[5];
    float* out = (float*)d_out;

    int n = in_sizes[0] / NDIMS;     // 2048

    float* featX = (float*)d_ws;
    float* featY = featX + (size_t)n * FSTR;

    int npts = 2 * n;
    hipLaunchKernelGGL(feat_kernel, dim3((npts + 3) / 4), dim3(256), 0, stream,
                       x, y, n, W1, b1, W2, b2, featX, featY);

    dim3 grid((n + 256 * JPT - 1) / (256 * JPT), (n + IT - 1) / IT);
    hipLaunchKernelGGL(pair_kernel, grid, dim3(256), 0, stream,
                       x, y, n, featX, featY, out);
}